// Round 1
// baseline (55082.062 us; speedup 1.0000x reference)
//
#include <hip/hip_runtime.h>
#include <math.h>

#define T_ 512
#define B_ 256
#define F_ 128
#define R_ 256
#define L_ 64

__device__ __forceinline__ float sigmoidf_(float x) { return 1.f / (1.f + expf(-x)); }
__device__ __forceinline__ float softplusf_(float x) {
    // stable log(1+exp(x))
    return fmaxf(x, 0.f) + log1pf(expf(-fabsf(x)));
}

// ---------------------------------------------------------------------------
// Small GEMM: C[M,N] = act(concat(A1,A2) @ W^T + bias), 16x16 tiles.
// Grid: (N/16, M/16), block (16,16). W is [N, K1+K2] row-major.
// ---------------------------------------------------------------------------
template<int ACT>
__global__ __launch_bounds__(256)
void gemm16k(const float* __restrict__ A1, int K1,
             const float* __restrict__ A2, int K2,
             const float* __restrict__ W,
             const float* __restrict__ bias,
             float* __restrict__ C, int N)
{
    __shared__ float As[16][17];
    __shared__ float Bs[16][17];
    const int tx = threadIdx.x, ty = threadIdx.y;
    const size_t row = blockIdx.y * 16 + ty;
    const int col = blockIdx.x * 16 + tx;
    const int K = K1 + K2;
    float acc = 0.f;
    for (int k0 = 0; k0 < K; k0 += 16) {
        int kk = k0 + tx;
        As[ty][tx] = (kk < K1) ? A1[row * K1 + kk] : A2[row * K2 + (kk - K1)];
        int wr = blockIdx.x * 16 + ty;
        Bs[ty][tx] = W[(size_t)wr * K + kk];
        __syncthreads();
#pragma unroll
        for (int k = 0; k < 16; ++k)
            acc = fmaf(As[ty][k], Bs[tx][k], acc);
        __syncthreads();
    }
    if (bias) acc += bias[col];
    if (ACT == 1) acc = fmaxf(acc, 0.f);
    C[row * N + col] = acc;
}

// ---------------------------------------------------------------------------
// Big batched GEMM: 64x64 tile per 256-thread block, 4x4 per thread.
// Grid: (N/64, M/64). C = act(concat(A1,A2) @ W^T + bias)
// ---------------------------------------------------------------------------
template<int ACT>
__global__ __launch_bounds__(256)
void gemm64k(const float* __restrict__ A1, int K1,
             const float* __restrict__ A2, int K2,
             const float* __restrict__ W,
             const float* __restrict__ bias,
             float* __restrict__ C, int N)
{
    __shared__ float As[16][68];  // [k][m], padded so float4 stays 16B-aligned
    __shared__ float Bs[16][68];  // [k][n]
    const int tid = threadIdx.y * 16 + threadIdx.x;
    const int lk = tid & 15, lg = tid >> 4;
    const int K = K1 + K2;
    const size_t m0 = (size_t)blockIdx.y * 64;
    const int n0 = blockIdx.x * 64;
    float acc[4][4] = {};
    for (int k0 = 0; k0 < K; k0 += 16) {
        int kk = k0 + lk;
#pragma unroll
        for (int i = 0; i < 4; ++i) {
            int m = lg + i * 16;
            As[lk][m] = (kk < K1) ? A1[(m0 + m) * K1 + kk]
                                  : A2[(m0 + m) * K2 + (kk - K1)];
            int n = lg + i * 16;
            Bs[lk][n] = W[(size_t)(n0 + n) * K + kk];
        }
        __syncthreads();
#pragma unroll
        for (int k = 0; k < 16; ++k) {
            float4 a4 = *(const float4*)&As[k][threadIdx.y * 4];
            float4 b4 = *(const float4*)&Bs[k][threadIdx.x * 4];
            float av[4] = {a4.x, a4.y, a4.z, a4.w};
            float bv[4] = {b4.x, b4.y, b4.z, b4.w};
#pragma unroll
            for (int i = 0; i < 4; ++i)
#pragma unroll
                for (int j = 0; j < 4; ++j)
                    acc[i][j] = fmaf(av[i], bv[j], acc[i][j]);
        }
        __syncthreads();
    }
#pragma unroll
    for (int i = 0; i < 4; ++i) {
        size_t m = m0 + threadIdx.y * 4 + i;
        float4 o;
        float* op = &o.x;
#pragma unroll
        for (int j = 0; j < 4; ++j) {
            int n = n0 + threadIdx.x * 4 + j;
            float v = acc[i][j];
            if (bias) v += bias[n];
            if (ACT == 1) v = fmaxf(v, 0.f);
            op[j] = v;
        }
        *(float4*)&C[m * N + n0 + threadIdx.x * 4] = o;
    }
}

// ---------------------------------------------------------------------------
// gh0 = h0 @ ghh0^T ; gh1 = h1 @ ghh1^T  (both M=256, N=768, K=256), z picks
// ---------------------------------------------------------------------------
__global__ __launch_bounds__(256)
void ghh_pair(const float* __restrict__ h0, const float* __restrict__ W0,
              const float* __restrict__ h1, const float* __restrict__ W1,
              float* __restrict__ g0, float* __restrict__ g1)
{
    const float* A = blockIdx.z ? h1 : h0;
    const float* W = blockIdx.z ? W1 : W0;
    float* C = blockIdx.z ? g1 : g0;
    __shared__ float As[16][17];
    __shared__ float Bs[16][17];
    const int tx = threadIdx.x, ty = threadIdx.y;
    const size_t row = blockIdx.y * 16 + ty;
    const int col = blockIdx.x * 16 + tx;
    float acc = 0.f;
    for (int k0 = 0; k0 < 256; k0 += 16) {
        int kk = k0 + tx;
        As[ty][tx] = A[row * 256 + kk];
        Bs[ty][tx] = W[(size_t)(blockIdx.x * 16 + ty) * 256 + kk];
        __syncthreads();
#pragma unroll
        for (int k = 0; k < 16; ++k)
            acc = fmaf(As[ty][k], Bs[tx][k], acc);
        __syncthreads();
    }
    C[row * 768 + col] = acc;
}

// ---------------------------------------------------------------------------
// enc: em = sigmoid(eo@emw^T+emb), es = softplus(eo@esw^T+esb), z = eps*es+em
// M=256, N=64, K=256. Grid (4,16).
// ---------------------------------------------------------------------------
__global__ __launch_bounds__(256)
void enc_kernel(const float* __restrict__ eo,
                const float* __restrict__ emw, const float* __restrict__ emb,
                const float* __restrict__ esw, const float* __restrict__ esb,
                const float* __restrict__ eps_t,
                float* __restrict__ em_out, float* __restrict__ es_out,
                float* __restrict__ zbuf)
{
    __shared__ float As[16][17], Wm[16][17], Ws[16][17];
    const int tx = threadIdx.x, ty = threadIdx.y;
    const size_t row = blockIdx.y * 16 + ty;
    const int col0 = blockIdx.x * 16;
    const int col = col0 + tx;
    float accm = 0.f, accs = 0.f;
    for (int k0 = 0; k0 < 256; k0 += 16) {
        int kk = k0 + tx;
        As[ty][tx] = eo[row * 256 + kk];
        Wm[ty][tx] = emw[(size_t)(col0 + ty) * 256 + kk];
        Ws[ty][tx] = esw[(size_t)(col0 + ty) * 256 + kk];
        __syncthreads();
#pragma unroll
        for (int k = 0; k < 16; ++k) {
            float a = As[ty][k];
            accm = fmaf(a, Wm[tx][k], accm);
            accs = fmaf(a, Ws[tx][k], accs);
        }
        __syncthreads();
    }
    float mu = sigmoidf_(accm + emb[col]);
    float sg = softplusf_(accs + esb[col]);
    em_out[row * L_ + col] = mu;
    es_out[row * L_ + col] = sg;
    zbuf[row * L_ + col] = eps_t[row * L_ + col] * sg + mu;
}

// ---------------------------------------------------------------------------
// GRU cell: gi = concat(A1,A2) @ Wih^T (3 gate tiles), gates with gh, hprev
// M=256, gate width 256. Grid (16,16).
// ---------------------------------------------------------------------------
__global__ __launch_bounds__(256)
void gru_kernel(const float* __restrict__ A1, int K1,
                const float* __restrict__ A2, int K2,
                const float* __restrict__ Wih,   // [768,K]
                const float* __restrict__ gh,    // [256,768]
                const float* __restrict__ hprev, // [256,256]
                float* __restrict__ hout)        // [256,256]
{
    __shared__ float As[16][17], Wr[16][17], Wz[16][17], Wn[16][17];
    const int tx = threadIdx.x, ty = threadIdx.y;
    const size_t row = blockIdx.y * 16 + ty;
    const int col0 = blockIdx.x * 16;
    const int col = col0 + tx;
    const int K = K1 + K2;
    float ar = 0.f, az = 0.f, an = 0.f;
    for (int k0 = 0; k0 < K; k0 += 16) {
        int kk = k0 + tx;
        As[ty][tx] = (kk < K1) ? A1[row * K1 + kk] : A2[row * K2 + (kk - K1)];
        Wr[ty][tx] = Wih[(size_t)(col0 + ty) * K + kk];
        Wz[ty][tx] = Wih[(size_t)(256 + col0 + ty) * K + kk];
        Wn[ty][tx] = Wih[(size_t)(512 + col0 + ty) * K + kk];
        __syncthreads();
#pragma unroll
        for (int k = 0; k < 16; ++k) {
            float a = As[ty][k];
            ar = fmaf(a, Wr[tx][k], ar);
            az = fmaf(a, Wz[tx][k], az);
            an = fmaf(a, Wn[tx][k], an);
        }
        __syncthreads();
    }
    float ghr = gh[row * 768 + col];
    float ghz = gh[row * 768 + 256 + col];
    float ghn = gh[row * 768 + 512 + col];
    float r = sigmoidf_(ar + ghr);
    float zg = sigmoidf_(az + ghz);
    float n = tanhf(an + r * ghn);
    float hv = hprev[row * 256 + col];
    hout[row * 256 + col] = (1.f - zg) * n + zg * hv;
}

// ---------------------------------------------------------------------------
// Decoder epilogue: dm = sigmoid(do@dmw^T+dmb), ds = softplus(do@dsw^T+dsb),
// nll partials. M=TB, N=128, K=256. Grid (8, TB/16).
// ---------------------------------------------------------------------------
__global__ __launch_bounds__(256)
void dec_kernel(const float* __restrict__ dox,
                const float* __restrict__ dmw, const float* __restrict__ dmb,
                const float* __restrict__ dsw, const float* __restrict__ dsb,
                const float* __restrict__ x,
                float* __restrict__ dm_out, float* __restrict__ ds_out,
                float* __restrict__ nllp)
{
    __shared__ float As[16][17], Wm[16][17], Ws[16][17];
    __shared__ float red[256];
    const int tx = threadIdx.x, ty = threadIdx.y;
    const size_t row = (size_t)blockIdx.y * 16 + ty;
    const int col0 = blockIdx.x * 16;
    const int col = col0 + tx;
    float accm = 0.f, accs = 0.f;
    for (int k0 = 0; k0 < 256; k0 += 16) {
        int kk = k0 + tx;
        As[ty][tx] = dox[row * 256 + kk];
        Wm[ty][tx] = dmw[(size_t)(col0 + ty) * 256 + kk];
        Ws[ty][tx] = dsw[(size_t)(col0 + ty) * 256 + kk];
        __syncthreads();
#pragma unroll
        for (int k = 0; k < 16; ++k) {
            float a = As[ty][k];
            accm = fmaf(a, Wm[tx][k], accm);
            accs = fmaf(a, Ws[tx][k], accs);
        }
        __syncthreads();
    }
    float um = accm + dmb[col];
    float us = accs + dsb[col];
    float dm = sigmoidf_(um);
    float dsg = softplusf_(us);
    dm_out[row * F_ + col] = dm;
    ds_out[row * F_ + col] = dsg;
    float xv = x[row * F_ + col];
    // -log(dm) = softplus(-um); -log(1-dm) = softplus(um)  (stable)
    float nl = xv * softplusf_(-um) + (1.f - xv) * softplusf_(um);
    int tid = ty * 16 + tx;
    red[tid] = nl;
    __syncthreads();
    for (int s = 128; s > 0; s >>= 1) {
        if (tid < s) red[tid] += red[tid + s];
        __syncthreads();
    }
    if (tid == 0) nllp[(size_t)blockIdx.y * gridDim.x + blockIdx.x] = red[0];
}

// ---------------------------------------------------------------------------
// Prior epilogue + KLD: pm = sigmoid(pr@pmw^T+pmb), ps = softplus(pr@psw^T+psb)
// kld partials vs stored em/es. M=TB, N=64, K=256. Grid (4, TB/16).
// ---------------------------------------------------------------------------
__global__ __launch_bounds__(256)
void kld_kernel(const float* __restrict__ pr,
                const float* __restrict__ pmw, const float* __restrict__ pmb,
                const float* __restrict__ psw, const float* __restrict__ psb,
                const float* __restrict__ em, const float* __restrict__ es,
                float* __restrict__ kldp)
{
    __shared__ float As[16][17], Wm[16][17], Ws[16][17];
    __shared__ float red[256];
    const int tx = threadIdx.x, ty = threadIdx.y;
    const size_t row = (size_t)blockIdx.y * 16 + ty;
    const int col0 = blockIdx.x * 16;
    const int col = col0 + tx;
    float accm = 0.f, accs = 0.f;
    for (int k0 = 0; k0 < 256; k0 += 16) {
        int kk = k0 + tx;
        As[ty][tx] = pr[row * 256 + kk];
        Wm[ty][tx] = pmw[(size_t)(col0 + ty) * 256 + kk];
        Ws[ty][tx] = psw[(size_t)(col0 + ty) * 256 + kk];
        __syncthreads();
#pragma unroll
        for (int k = 0; k < 16; ++k) {
            float a = As[ty][k];
            accm = fmaf(a, Wm[tx][k], accm);
            accs = fmaf(a, Ws[tx][k], accs);
        }
        __syncthreads();
    }
    float pm = sigmoidf_(accm + pmb[col]);
    float ps = softplusf_(accs + psb[col]);
    float e_m = em[row * L_ + col];
    float e_s = es[row * L_ + col];
    float d = e_m - pm;
    float kl = 0.5f * (2.f * (logf(ps) - logf(e_s)) +
                       (e_s * e_s + d * d) / (ps * ps) - 1.f);
    int tid = ty * 16 + tx;
    red[tid] = kl;
    __syncthreads();
    for (int s = 128; s > 0; s >>= 1) {
        if (tid < s) red[tid] += red[tid + s];
        __syncthreads();
    }
    if (tid == 0) kldp[(size_t)blockIdx.y * gridDim.x + blockIdx.x] = red[0];
}

// ---------------------------------------------------------------------------
// Final reduce: out[0] = sum kldp, out[1] = sum nllp
// ---------------------------------------------------------------------------
__global__ __launch_bounds__(256)
void final_reduce(const float* __restrict__ kldp, int n_kld,
                  const float* __restrict__ nllp, int n_nll,
                  float* __restrict__ out)
{
    const float* src = (blockIdx.x == 0) ? kldp : nllp;
    int n = (blockIdx.x == 0) ? n_kld : n_nll;
    __shared__ float red[256];
    int tid = threadIdx.x;
    float s = 0.f;
    for (int i = tid; i < n; i += 256) s += src[i];
    red[tid] = s;
    __syncthreads();
    for (int st = 128; st > 0; st >>= 1) {
        if (tid < st) red[tid] += red[tid + st];
        __syncthreads();
    }
    if (tid == 0) out[blockIdx.x] = red[0];
}

extern "C" void kernel_launch(void* const* d_in, const int* in_sizes, int n_in,
                              void* d_out, int out_size, void* d_ws, size_t ws_size,
                              hipStream_t stream)
{
    const float* x    = (const float*)d_in[0];
    const float* eps  = (const float*)d_in[1];
    const float* pxw1 = (const float*)d_in[2];
    const float* pxb1 = (const float*)d_in[3];
    const float* pxw2 = (const float*)d_in[4];
    const float* pxb2 = (const float*)d_in[5];
    const float* pzw1 = (const float*)d_in[6];
    const float* pzb1 = (const float*)d_in[7];
    const float* pzw2 = (const float*)d_in[8];
    const float* pzb2 = (const float*)d_in[9];
    const float* ew1  = (const float*)d_in[10];
    const float* eb1  = (const float*)d_in[11];
    const float* ew2  = (const float*)d_in[12];
    const float* eb2  = (const float*)d_in[13];
    const float* emw  = (const float*)d_in[14];
    const float* emb  = (const float*)d_in[15];
    const float* esw  = (const float*)d_in[16];
    const float* esb  = (const float*)d_in[17];
    const float* prw  = (const float*)d_in[18];
    const float* prb  = (const float*)d_in[19];
    const float* pmw  = (const float*)d_in[20];
    const float* pmb  = (const float*)d_in[21];
    const float* psw  = (const float*)d_in[22];
    const float* psb  = (const float*)d_in[23];
    const float* dw1  = (const float*)d_in[24];
    const float* db1  = (const float*)d_in[25];
    const float* dw2  = (const float*)d_in[26];
    const float* db2  = (const float*)d_in[27];
    const float* dmw  = (const float*)d_in[28];
    const float* dmb  = (const float*)d_in[29];
    const float* dsw  = (const float*)d_in[30];
    const float* dsb  = (const float*)d_in[31];
    const float* gih0 = (const float*)d_in[32];
    const float* ghh0 = (const float*)d_in[33];
    const float* gih1 = (const float*)d_in[34];
    const float* ghh1 = (const float*)d_in[35];

    float* out = (float*)d_out;
    float* ws  = (float*)d_ws;

    const size_t TB = (size_t)T_ * B_;  // 131072

    float* phi_x = ws;                                   // TB*256
    float* phi_z = phi_x + TB * 256;                     // TB*256
    float* hlast = phi_z + TB * 256;                     // (T+1)*B*256
    float* h0b   = hlast + (size_t)(T_ + 1) * B_ * 256;  // 2*B*256
    float* e1    = h0b + 2 * B_ * 256;                   // B*256
    float* eo    = e1 + B_ * 256;                        // B*256
    float* zb    = eo + B_ * 256;                        // B*64
    float* pz1   = zb + B_ * L_;                         // B*256
    float* gh0   = pz1 + B_ * 256;                       // B*768
    float* gh1   = gh0 + B_ * 768;                       // B*768
    float* nllp  = gh1 + B_ * 768;                       // 65536
    float* kldp  = nllp + 65536;                         // 32768

    float* em_out = out + 2;
    float* es_out = em_out + TB * L_;
    float* dm_out = es_out + TB * L_;
    float* ds_out = dm_out + TB * F_;

    dim3 blk(16, 16);

    // zero h0 (ping slot 0) and hlast slot 0
    hipMemsetAsync(h0b, 0, (size_t)B_ * 256 * sizeof(float), stream);
    hipMemsetAsync(hlast, 0, (size_t)B_ * 256 * sizeof(float), stream);

    // ---- phase 1: phi_x for all (t,b), batched ----
    gemm64k<1><<<dim3(4, TB / 64), blk, 0, stream>>>(x, F_, nullptr, 0, pxw1, pxb1, phi_z, 256);
    gemm64k<1><<<dim3(4, TB / 64), blk, 0, stream>>>(phi_z, 256, nullptr, 0, pxw2, pxb2, phi_x, 256);

    // ---- phase 2: sequential scan ----
    for (int t = 0; t < T_; ++t) {
        const float* phix_t = phi_x + (size_t)t * B_ * 256;
        float* phiz_t = phi_z + (size_t)t * B_ * 256;
        const float* h1 = hlast + (size_t)t * B_ * 256;
        float* h1n = hlast + (size_t)(t + 1) * B_ * 256;
        const float* h0c = h0b + (size_t)(t & 1) * B_ * 256;
        float* h0n = h0b + (size_t)((t + 1) & 1) * B_ * 256;

        gemm16k<1><<<dim3(16, 16), blk, 0, stream>>>(phix_t, 256, h1, 256, ew1, eb1, e1, 256);
        ghh_pair<<<dim3(48, 16, 2), blk, 0, stream>>>(h0c, ghh0, h1, ghh1, gh0, gh1);
        gemm16k<1><<<dim3(16, 16), blk, 0, stream>>>(e1, 256, nullptr, 0, ew2, eb2, eo, 256);
        enc_kernel<<<dim3(4, 16), blk, 0, stream>>>(eo, emw, emb, esw, esb,
            eps + (size_t)t * B_ * L_, em_out + (size_t)t * B_ * L_,
            es_out + (size_t)t * B_ * L_, zb);
        gemm16k<1><<<dim3(16, 16), blk, 0, stream>>>(zb, L_, nullptr, 0, pzw1, pzb1, pz1, 256);
        gemm16k<1><<<dim3(16, 16), blk, 0, stream>>>(pz1, 256, nullptr, 0, pzw2, pzb2, phiz_t, 256);
        gru_kernel<<<dim3(16, 16), blk, 0, stream>>>(phix_t, 256, phiz_t, 256, gih0, gh0, h0c, h0n);
        gru_kernel<<<dim3(16, 16), blk, 0, stream>>>(h0n, 256, nullptr, 0, gih1, gh1, h1, h1n);
    }

    // ---- phase 3: batched decoder / prior / reductions ----
    // d1 = relu([phi_z | hlast] @ dw1^T + db1)  -> reuse phi_x buffer
    gemm64k<1><<<dim3(4, TB / 64), blk, 0, stream>>>(phi_z, 256, hlast, 256, dw1, db1, phi_x, 256);
    // do = relu(d1 @ dw2^T + db2) -> reuse phi_z buffer
    gemm64k<1><<<dim3(4, TB / 64), blk, 0, stream>>>(phi_x, 256, nullptr, 0, dw2, db2, phi_z, 256);
    // dec_mu / dec_sig / nll partials
    dec_kernel<<<dim3(8, TB / 16), blk, 0, stream>>>(phi_z, dmw, dmb, dsw, dsb, x,
                                                     dm_out, ds_out, nllp);
    // pr = relu(hlast @ prw^T + prb) -> reuse phi_x buffer
    gemm64k<1><<<dim3(4, TB / 64), blk, 0, stream>>>(hlast, 256, nullptr, 0, prw, prb, phi_x, 256);
    // pr_mu / pr_sig / kld partials
    kld_kernel<<<dim3(4, TB / 16), blk, 0, stream>>>(phi_x, pmw, pmb, psw, psb,
                                                     em_out, es_out, kldp);
    // final sums
    final_reduce<<<2, 256, 0, stream>>>(kldp, 4 * (int)(TB / 16),
                                        nllp, 8 * (int)(TB / 16), out);
}

// Round 2
// 52959.283 us; speedup vs baseline: 1.0401x; 1.0401x over previous
//
#include <hip/hip_runtime.h>
#include <hip/hip_bf16.h>
#include <math.h>

#define T_ 512
#define B_ 256
#define F_ 128
#define R_ 256
#define L_ 64
#define TB_ ((size_t)T_ * B_)

typedef short bh8 __attribute__((ext_vector_type(8)));
typedef float f32x4 __attribute__((ext_vector_type(4)));
typedef unsigned short u16;

#define MFMA16(a, b, c) __builtin_amdgcn_mfma_f32_16x16x32_bf16((a), (b), (c), 0, 0, 0)

__device__ __forceinline__ float sigmoidf_(float x) { return 1.f / (1.f + __expf(-x)); }
__device__ __forceinline__ float softplusf_(float x) {
    return fmaxf(x, 0.f) + log1pf(expf(-fabsf(x)));
}
__device__ __forceinline__ u16 bf16bits(float v) {
    __hip_bfloat16 h = __float2bfloat16(v);
    return *reinterpret_cast<u16*>(&h);
}

// ---------------------------------------------------------------------------
// Weight packing: fp32 [N][K] row-major -> bf16 MFMA-B fragments.
// Fragment (nt,kt): lane l holds B[n = nt*16 + (l&15)][k = kt*32 + (l>>4)*8 + j]
// flat: dst[(((nt*KT + kt)*64) + l)*8 + j]
// ---------------------------------------------------------------------------
__global__ __launch_bounds__(256) void pack_w(const float* __restrict__ src,
                                              u16* __restrict__ dst, int N, int K) {
    int idx = blockIdx.x * 256 + threadIdx.x;
    if (idx >= N * K) return;
    int n = idx / K, k = idx - n * K;
    int nt = n >> 4, kt = k >> 5, KT = K >> 5;
    size_t di = ((size_t)(nt * KT + kt) * 64 + ((k >> 3) & 3) * 16 + (n & 15)) * 8 + (k & 7);
    dst[di] = bf16bits(src[idx]);
}

// Interleaved pair packing: logical N=128, even tiles from A, odd from B.
__global__ __launch_bounds__(256) void pack_pair(const float* __restrict__ sA,
                                                 const float* __restrict__ sB,
                                                 u16* __restrict__ dst, int K) {
    int idx = blockIdx.x * 256 + threadIdx.x;
    if (idx >= 128 * K) return;
    int n = idx / K, k = idx - n * K;
    int nt = n >> 4, nin = n & 15, KT = K >> 5;
    const float* s = (nt & 1) ? sB : sA;
    float v = s[(size_t)((nt >> 1) * 16 + nin) * K + k];
    size_t di = ((size_t)(nt * KT + (k >> 5)) * 64 + ((k >> 3) & 3) * 16 + nin) * 8 + (k & 7);
    dst[di] = bf16bits(v);
}

__global__ __launch_bounds__(256) void cvt_bf16(const float* __restrict__ src,
                                                u16* __restrict__ dst, size_t n) {
    for (size_t i = blockIdx.x * 256ull + threadIdx.x; i < n; i += (size_t)gridDim.x * 256)
        dst[i] = bf16bits(src[i]);
}

// ---------------------------------------------------------------------------
// Batched MFMA GEMM: C[M=TB][N] = epi(concat(A1,A2) @ W^T + b), 128x128 tile.
// 256 threads = 4 waves, wave (wr,wc) owns 64x64 quadrant (4x4 16x16 frags).
// A staged to LDS (swizzled), B fragments loaded directly from packed global.
// EPI: 0 = relu -> bf16 out; 1 = dec heads (dm sigmoid / ds softplus + nll);
//      2 = prior heads paired (pm/ps interleaved tiles) + kld partials.
// ---------------------------------------------------------------------------
template <int EPI>
__global__ __launch_bounds__(256) void gemmB(
    const u16* __restrict__ A1, int K1, const u16* __restrict__ A2, int K2,
    const bh8* __restrict__ Wp, int KT,
    const float* __restrict__ b1, const float* __restrict__ b2,
    u16* __restrict__ obf, int Nout,
    float* __restrict__ o1, float* __restrict__ o2,
    const float* __restrict__ aux1, const float* __restrict__ aux2,
    float* __restrict__ partial) {
    __shared__ __align__(16) char As[8192];
    __shared__ float red[256];
    const int tid = threadIdx.x, w = tid >> 6, l = tid & 63, l15 = l & 15, lq = l >> 4;
    const int wr = w >> 1, wc = w & 1;
    const size_t m0 = (size_t)blockIdx.y * 128;
    f32x4 acc[4][4];
#pragma unroll
    for (int i = 0; i < 4; ++i)
#pragma unroll
        for (int j = 0; j < 4; ++j) acc[i][j] = f32x4{0.f, 0.f, 0.f, 0.f};

    for (int kt = 0; kt < KT; ++kt) {
#pragma unroll
        for (int cc = 0; cc < 2; ++cc) {
            int c = tid + cc * 256;
            int r = c >> 2, j = c & 3;
            int kg = kt * 32 + j * 8;
            const u16* src = (kg < K1) ? (A1 + (m0 + r) * (size_t)K1 + kg)
                                       : (A2 + (m0 + r) * (size_t)K2 + (kg - K1));
            bh8 v = *(const bh8*)src;
            *(bh8*)(As + r * 64 + ((j * 16) ^ ((r & 7) << 4))) = v;
        }
        __syncthreads();
        bh8 bfr[4];
#pragma unroll
        for (int nt = 0; nt < 4; ++nt)
            bfr[nt] = Wp[((size_t)(blockIdx.x * 8 + wc * 4 + nt) * KT + kt) * 64 + l];
#pragma unroll
        for (int mt = 0; mt < 4; ++mt) {
            int rrow = (wr * 4 + mt) * 16 + l15;
            bh8 a = *(const bh8*)(As + rrow * 64 + ((lq * 16) ^ ((rrow & 7) << 4)));
#pragma unroll
            for (int nt = 0; nt < 4; ++nt) acc[mt][nt] = MFMA16(a, bfr[nt], acc[mt][nt]);
        }
        __syncthreads();
    }

    float part = 0.f;
#pragma unroll
    for (int mt = 0; mt < 4; ++mt) {
        if (EPI == 0 || EPI == 1) {
#pragma unroll
            for (int nt = 0; nt < 4; ++nt) {
                int gt = blockIdx.x * 8 + wc * 4 + nt;
#pragma unroll
                for (int rr = 0; rr < 4; ++rr) {
                    size_t row = m0 + (wr * 4 + mt) * 16 + lq * 4 + rr;
                    float v = acc[mt][nt][rr];
                    if (EPI == 0) {
                        int col = gt * 16 + l15;
                        obf[row * Nout + col] = bf16bits(fmaxf(v + b1[col], 0.f));
                    } else {
                        if (gt < 8) {
                            int col = gt * 16 + l15;
                            float u = v + b1[col];
                            o1[row * 128 + col] = sigmoidf_(u);
                            float xv = aux1[row * 128 + col];
                            part += xv * softplusf_(-u) + (1.f - xv) * softplusf_(u);
                        } else {
                            int col = (gt - 8) * 16 + l15;
                            o2[row * 128 + col] = softplusf_(v + b2[col]);
                        }
                    }
                }
            }
        } else {  // EPI == 2: paired pm/ps tiles
#pragma unroll
            for (int np = 0; np < 2; ++np) {
                int col = (wc * 2 + np) * 16 + l15;
#pragma unroll
                for (int rr = 0; rr < 4; ++rr) {
                    size_t row = m0 + (wr * 4 + mt) * 16 + lq * 4 + rr;
                    float um = acc[mt][2 * np][rr] + b1[col];
                    float us = acc[mt][2 * np + 1][rr] + b2[col];
                    float pm = sigmoidf_(um);
                    float ps = softplusf_(us);
                    float em = aux1[row * 64 + col];
                    float es = aux2[row * 64 + col];
                    float d = em - pm;
                    part += 0.5f * (2.f * (logf(ps) - logf(es)) +
                                    (es * es + d * d) / (ps * ps) - 1.f);
                }
            }
        }
    }
    if (EPI != 0) {
        __syncthreads();
        red[tid] = part;
        __syncthreads();
        for (int s = 128; s > 0; s >>= 1) {
            if (tid < s) red[tid] += red[tid + s];
            __syncthreads();
        }
        if (tid == 0) partial[(size_t)blockIdx.y * gridDim.x + blockIdx.x] = red[0];
    }
}

// ---------------------------------------------------------------------------
// Persistent scan: 16 workgroups x 512 threads (8 waves). WG owns 16 rows,
// runs all 512 steps. Activations bf16 in LDS (XOR-swizzled rows), weights
// streamed as packed MFMA B-fragments from L2.
// ---------------------------------------------------------------------------
#define CAT1 0        // [16][512] bf16 : phi_x | (h1 -> phi_z -> h1n)
#define H0B 16384     // [16][256] bf16 : h0
#define E1S 24576     // [16][256] bf16
#define EOS 32768     // [16][256] bf16
#define ZS 40960      // [16][64]  bf16
#define PZ1S 43008    // [16][256] bf16
#define H0F 51200     // [16][256] f32
#define H1F 67584     // [16][256] f32
#define SMEM_BYTES 83968

__device__ __forceinline__ bh8 lds_afrag(const char* smem, int base, int stride,
                                         int r, int kb) {
    return *(const bh8*)(smem + base + r * stride + (kb ^ ((r & 7) << 4)));
}
__device__ __forceinline__ void lds_st16(char* smem, int base, int stride, int r,
                                         int c, float v) {
    *(u16*)(smem + base + r * stride + ((c * 2) ^ ((r & 7) << 4))) = bf16bits(v);
}

__global__ __launch_bounds__(512, 1) void scan_kernel(
    const u16* __restrict__ phix_g, const float* __restrict__ eps_g,
    const bh8* __restrict__ ew1p, const float* __restrict__ eb1,
    const bh8* __restrict__ ew2p, const float* __restrict__ eb2,
    const bh8* __restrict__ emwp, const float* __restrict__ emb,
    const bh8* __restrict__ eswp, const float* __restrict__ esb,
    const bh8* __restrict__ pzw1p, const float* __restrict__ pzb1,
    const bh8* __restrict__ pzw2p, const float* __restrict__ pzb2,
    const bh8* __restrict__ gih0p, const bh8* __restrict__ ghh0p,
    const bh8* __restrict__ gih1p, const bh8* __restrict__ ghh1p,
    float* __restrict__ em_out, float* __restrict__ es_out,
    u16* __restrict__ phiz_g, u16* __restrict__ hst_g) {
    __shared__ __align__(16) char smem[SMEM_BYTES];
    const int tid = threadIdx.x;
    const int w = tid >> 6, l = tid & 63, l15 = l & 15, lq = l >> 4;
    const int row0 = blockIdx.x * 16;
    const int gtile0 = 2 * w, gtile1 = 2 * w + 1;

    for (int i = tid * 16; i < SMEM_BYTES; i += 512 * 16)
        *(int4*)(smem + i) = int4{0, 0, 0, 0};
    for (int i = tid; i < 16 * 256; i += 512)
        hst_g[(size_t)(row0 + (i >> 8)) * 256 + (i & 255)] = 0;
    {
        int r = tid >> 5, ch = tid & 31;
        bh8 v = *(const bh8*)(phix_g + ((size_t)row0 + r) * 256 + ch * 8);
        *(bh8*)(smem + CAT1 + r * 1024 + ((ch * 16) ^ ((r & 7) << 4))) = v;
    }
    __syncthreads();

    for (int t = 0; t < T_; ++t) {
        // ---- S1: e1 (2 tiles, K=512) + gh0, gh1 (6 tiles each, K=256) ----
        f32x4 e1a0 = {0.f, 0.f, 0.f, 0.f}, e1a1 = {0.f, 0.f, 0.f, 0.f};
#pragma unroll
        for (int kt = 0; kt < 16; ++kt) {
            bh8 a = lds_afrag(smem, CAT1, 1024, l15, kt * 64 + lq * 16);
            e1a0 = MFMA16(a, ew1p[(size_t)(gtile0 * 16 + kt) * 64 + l], e1a0);
            e1a1 = MFMA16(a, ew1p[(size_t)(gtile1 * 16 + kt) * 64 + l], e1a1);
        }
        f32x4 gh0a[6], gh1a[6];
#pragma unroll
        for (int q = 0; q < 6; ++q) { gh0a[q] = f32x4{0.f,0.f,0.f,0.f}; gh1a[q] = f32x4{0.f,0.f,0.f,0.f}; }
#pragma unroll
        for (int kt = 0; kt < 8; ++kt) {
            bh8 a = lds_afrag(smem, H0B, 512, l15, kt * 64 + lq * 16);
#pragma unroll
            for (int q = 0; q < 6; ++q) {
                int gt = (q >> 1) * 16 + 2 * w + (q & 1);
                gh0a[q] = MFMA16(a, ghh0p[(size_t)(gt * 8 + kt) * 64 + l], gh0a[q]);
            }
        }
#pragma unroll
        for (int kt = 0; kt < 8; ++kt) {
            bh8 a = lds_afrag(smem, CAT1, 1024, l15, 512 + kt * 64 + lq * 16);
#pragma unroll
            for (int q = 0; q < 6; ++q) {
                int gt = (q >> 1) * 16 + 2 * w + (q & 1);
                gh1a[q] = MFMA16(a, ghh1p[(size_t)(gt * 8 + kt) * 64 + l], gh1a[q]);
            }
        }
#pragma unroll
        for (int rr = 0; rr < 4; ++rr) {
            int r = lq * 4 + rr;
            int c0 = gtile0 * 16 + l15, c1 = gtile1 * 16 + l15;
            lds_st16(smem, E1S, 512, r, c0, fmaxf(e1a0[rr] + eb1[c0], 0.f));
            lds_st16(smem, E1S, 512, r, c1, fmaxf(e1a1[rr] + eb1[c1], 0.f));
        }
        __syncthreads();

        // ---- S2: eo (2 tiles, K=256) ----
        f32x4 eoa0 = {0.f, 0.f, 0.f, 0.f}, eoa1 = {0.f, 0.f, 0.f, 0.f};
#pragma unroll
        for (int kt = 0; kt < 8; ++kt) {
            bh8 a = lds_afrag(smem, E1S, 512, l15, kt * 64 + lq * 16);
            eoa0 = MFMA16(a, ew2p[(size_t)(gtile0 * 8 + kt) * 64 + l], eoa0);
            eoa1 = MFMA16(a, ew2p[(size_t)(gtile1 * 8 + kt) * 64 + l], eoa1);
        }
#pragma unroll
        for (int rr = 0; rr < 4; ++rr) {
            int r = lq * 4 + rr;
            int c0 = gtile0 * 16 + l15, c1 = gtile1 * 16 + l15;
            lds_st16(smem, EOS, 512, r, c0, fmaxf(eoa0[rr] + eb2[c0], 0.f));
            lds_st16(smem, EOS, 512, r, c1, fmaxf(eoa1[rr] + eb2[c1], 0.f));
        }
        __syncthreads();

        // ---- S3: enc heads (waves 0-3: em+es tile w), z = eps*es+em ----
        if (w < 4) {
            f32x4 am = {0.f, 0.f, 0.f, 0.f}, asg = {0.f, 0.f, 0.f, 0.f};
#pragma unroll
            for (int kt = 0; kt < 8; ++kt) {
                bh8 a = lds_afrag(smem, EOS, 512, l15, kt * 64 + lq * 16);
                am = MFMA16(a, emwp[(size_t)(w * 8 + kt) * 64 + l], am);
                asg = MFMA16(a, eswp[(size_t)(w * 8 + kt) * 64 + l], asg);
            }
            int c = w * 16 + l15;
#pragma unroll
            for (int rr = 0; rr < 4; ++rr) {
                int r = lq * 4 + rr;
                size_t gi = ((size_t)t * B_ + row0 + r) * 64 + c;
                float mu = sigmoidf_(am[rr] + emb[c]);
                float sg = softplusf_(asg[rr] + esb[c]);
                em_out[gi] = mu;
                es_out[gi] = sg;
                lds_st16(smem, ZS, 128, r, c, eps_g[gi] * sg + mu);
            }
        }
        __syncthreads();

        // ---- S4: pz1 (2 tiles, K=64) ----
        f32x4 p1a0 = {0.f, 0.f, 0.f, 0.f}, p1a1 = {0.f, 0.f, 0.f, 0.f};
#pragma unroll
        for (int kt = 0; kt < 2; ++kt) {
            bh8 a = lds_afrag(smem, ZS, 128, l15, kt * 64 + lq * 16);
            p1a0 = MFMA16(a, pzw1p[(size_t)(gtile0 * 2 + kt) * 64 + l], p1a0);
            p1a1 = MFMA16(a, pzw1p[(size_t)(gtile1 * 2 + kt) * 64 + l], p1a1);
        }
#pragma unroll
        for (int rr = 0; rr < 4; ++rr) {
            int r = lq * 4 + rr;
            int c0 = gtile0 * 16 + l15, c1 = gtile1 * 16 + l15;
            lds_st16(smem, PZ1S, 512, r, c0, fmaxf(p1a0[rr] + pzb1[c0], 0.f));
            lds_st16(smem, PZ1S, 512, r, c1, fmaxf(p1a1[rr] + pzb1[c1], 0.f));
        }
        __syncthreads();

        // ---- S5: phi_z (2 tiles, K=256) -> CAT1 cols 256.. + global stash ----
        f32x4 pza0 = {0.f, 0.f, 0.f, 0.f}, pza1 = {0.f, 0.f, 0.f, 0.f};
#pragma unroll
        for (int kt = 0; kt < 8; ++kt) {
            bh8 a = lds_afrag(smem, PZ1S, 512, l15, kt * 64 + lq * 16);
            pza0 = MFMA16(a, pzw2p[(size_t)(gtile0 * 8 + kt) * 64 + l], pza0);
            pza1 = MFMA16(a, pzw2p[(size_t)(gtile1 * 8 + kt) * 64 + l], pza1);
        }
#pragma unroll
        for (int rr = 0; rr < 4; ++rr) {
            int r = lq * 4 + rr;
#pragma unroll
            for (int p = 0; p < 2; ++p) {
                int c = (2 * w + p) * 16 + l15;
                float v = fmaxf((p ? pza1[rr] : pza0[rr]) + pzb2[c], 0.f);
                lds_st16(smem, CAT1, 1024, r, 256 + c, v);
                phiz_g[((size_t)t * B_ + row0 + r) * 256 + c] = bf16bits(v);
            }
        }
        __syncthreads();

        // ---- S6: gi0 (6 tiles, K=512) + GRU0 gates -> h0 ----
        f32x4 gia[6];
#pragma unroll
        for (int q = 0; q < 6; ++q) gia[q] = f32x4{0.f, 0.f, 0.f, 0.f};
#pragma unroll
        for (int kt = 0; kt < 16; ++kt) {
            bh8 a = lds_afrag(smem, CAT1, 1024, l15, kt * 64 + lq * 16);
#pragma unroll
            for (int q = 0; q < 6; ++q) {
                int gt = (q >> 1) * 16 + 2 * w + (q & 1);
                gia[q] = MFMA16(a, gih0p[(size_t)(gt * 16 + kt) * 64 + l], gia[q]);
            }
        }
#pragma unroll
        for (int p = 0; p < 2; ++p) {
            int c = (2 * w + p) * 16 + l15;
#pragma unroll
            for (int rr = 0; rr < 4; ++rr) {
                int r = lq * 4 + rr;
                float gr = sigmoidf_(gia[p][rr] + gh0a[p][rr]);
                float gz = sigmoidf_(gia[2 + p][rr] + gh0a[2 + p][rr]);
                float gn = tanhf(gia[4 + p][rr] + gr * gh0a[4 + p][rr]);
                float hp = *(const float*)(smem + H0F + r * 1024 + c * 4);
                float hn = (1.f - gz) * gn + gz * hp;
                *(float*)(smem + H0F + r * 1024 + c * 4) = hn;
                lds_st16(smem, H0B, 512, r, c, hn);
            }
        }
        __syncthreads();

        // ---- S7: gi1 (6 tiles, K=256, A=h0 new) + GRU1 gates -> h1 ----
#pragma unroll
        for (int q = 0; q < 6; ++q) gia[q] = f32x4{0.f, 0.f, 0.f, 0.f};
#pragma unroll
        for (int kt = 0; kt < 8; ++kt) {
            bh8 a = lds_afrag(smem, H0B, 512, l15, kt * 64 + lq * 16);
#pragma unroll
            for (int q = 0; q < 6; ++q) {
                int gt = (q >> 1) * 16 + 2 * w + (q & 1);
                gia[q] = MFMA16(a, gih1p[(size_t)(gt * 8 + kt) * 64 + l], gia[q]);
            }
        }
#pragma unroll
        for (int p = 0; p < 2; ++p) {
            int c = (2 * w + p) * 16 + l15;
#pragma unroll
            for (int rr = 0; rr < 4; ++rr) {
                int r = lq * 4 + rr;
                float gr = sigmoidf_(gia[p][rr] + gh1a[p][rr]);
                float gz = sigmoidf_(gia[2 + p][rr] + gh1a[2 + p][rr]);
                float gn = tanhf(gia[4 + p][rr] + gr * gh1a[4 + p][rr]);
                float hp = *(const float*)(smem + H1F + r * 1024 + c * 4);
                float hn = (1.f - gz) * gn + gz * hp;
                *(float*)(smem + H1F + r * 1024 + c * 4) = hn;
                lds_st16(smem, CAT1, 1024, r, 256 + c, hn);
                if (t < T_ - 1)
                    hst_g[((size_t)(t + 1) * B_ + row0 + r) * 256 + c] = bf16bits(hn);
            }
        }
        if (t < T_ - 1) {
            int r = tid >> 5, ch = tid & 31;
            bh8 v = *(const bh8*)(phix_g + ((size_t)(t + 1) * B_ + row0 + r) * 256 + ch * 8);
            *(bh8*)(smem + CAT1 + r * 1024 + ((ch * 16) ^ ((r & 7) << 4))) = v;
        }
        __syncthreads();
    }
}

__global__ __launch_bounds__(256) void final_reduce(const float* __restrict__ kldp,
                                                    int n_kld,
                                                    const float* __restrict__ nllp,
                                                    int n_nll, float* __restrict__ out) {
    const float* src = (blockIdx.x == 0) ? kldp : nllp;
    int n = (blockIdx.x == 0) ? n_kld : n_nll;
    __shared__ float red[256];
    int tid = threadIdx.x;
    float s = 0.f;
    for (int i = tid; i < n; i += 256) s += src[i];
    red[tid] = s;
    __syncthreads();
    for (int st = 128; st > 0; st >>= 1) {
        if (tid < st) red[tid] += red[tid + st];
        __syncthreads();
    }
    if (tid == 0) out[blockIdx.x] = red[0];
}

extern "C" void kernel_launch(void* const* d_in, const int* in_sizes, int n_in,
                              void* d_out, int out_size, void* d_ws, size_t ws_size,
                              hipStream_t stream) {
    const float* x = (const float*)d_in[0];
    const float* eps = (const float*)d_in[1];
    const float* pxw1 = (const float*)d_in[2];
    const float* pxb1 = (const float*)d_in[3];
    const float* pxw2 = (const float*)d_in[4];
    const float* pxb2 = (const float*)d_in[5];
    const float* pzw1 = (const float*)d_in[6];
    const float* pzb1 = (const float*)d_in[7];
    const float* pzw2 = (const float*)d_in[8];
    const float* pzb2 = (const float*)d_in[9];
    const float* ew1 = (const float*)d_in[10];
    const float* eb1 = (const float*)d_in[11];
    const float* ew2 = (const float*)d_in[12];
    const float* eb2 = (const float*)d_in[13];
    const float* emw = (const float*)d_in[14];
    const float* emb = (const float*)d_in[15];
    const float* esw = (const float*)d_in[16];
    const float* esb = (const float*)d_in[17];
    const float* prw = (const float*)d_in[18];
    const float* prb = (const float*)d_in[19];
    const float* pmw = (const float*)d_in[20];
    const float* pmb = (const float*)d_in[21];
    const float* psw = (const float*)d_in[22];
    const float* psb = (const float*)d_in[23];
    const float* dw1 = (const float*)d_in[24];
    const float* db1 = (const float*)d_in[25];
    const float* dw2 = (const float*)d_in[26];
    const float* db2 = (const float*)d_in[27];
    const float* dmw = (const float*)d_in[28];
    const float* dmb = (const float*)d_in[29];
    const float* dsw = (const float*)d_in[30];
    const float* dsb = (const float*)d_in[31];
    const float* gih0 = (const float*)d_in[32];
    const float* ghh0 = (const float*)d_in[33];
    const float* gih1 = (const float*)d_in[34];
    const float* ghh1 = (const float*)d_in[35];

    float* out = (float*)d_out;
    char* wsb = (char*)d_ws;

    // packed weight offsets (bytes)
    u16* ew1p = (u16*)(wsb + 0);
    u16* ew2p = (u16*)(wsb + 262144);
    u16* emwp = (u16*)(wsb + 393216);
    u16* eswp = (u16*)(wsb + 425984);
    u16* pzw1p = (u16*)(wsb + 458752);
    u16* pzw2p = (u16*)(wsb + 491520);
    u16* gih0p = (u16*)(wsb + 622592);
    u16* ghh0p = (u16*)(wsb + 1409024);
    u16* gih1p = (u16*)(wsb + 1802240);
    u16* ghh1p = (u16*)(wsb + 2195456);
    u16* pxw1p = (u16*)(wsb + 2588672);
    u16* pxw2p = (u16*)(wsb + 2654208);
    u16* dw1p = (u16*)(wsb + 2785280);
    u16* dw2p = (u16*)(wsb + 3047424);
    u16* decp = (u16*)(wsb + 3178496);   // dmw tiles 0-7, dsw tiles 8-15
    u16* priorp = (u16*)(wsb + 3309568); // pm/ps interleaved
    u16* prwp = (u16*)(wsb + 3375104);

    u16* xbf = (u16*)(wsb + 3506176);
    u16* t1 = (u16*)(wsb + 37060608);
    u16* phi_x = (u16*)(wsb + 104169472);
    u16* phi_z = (u16*)(wsb + 171278336);
    u16* hst = (u16*)(wsb + 238387200);
    u16* dox = (u16*)(wsb + 305496064);
    float* nllp = (float*)(wsb + 372604928);
    float* kldp = (float*)(wsb + 372613120);

    float* em_out = out + 2;
    float* es_out = em_out + TB_ * L_;
    float* dm_out = es_out + TB_ * L_;
    float* ds_out = dm_out + TB_ * F_;

    // ---- pack weights ----
    auto PK = [&](const float* s, u16* d, int N, int K) {
        pack_w<<<(N * K + 255) / 256, 256, 0, stream>>>(s, d, N, K);
    };
    PK(ew1, ew1p, 256, 512);
    PK(ew2, ew2p, 256, 256);
    PK(emw, emwp, 64, 256);
    PK(esw, eswp, 64, 256);
    PK(pzw1, pzw1p, 256, 64);
    PK(pzw2, pzw2p, 256, 256);
    PK(gih0, gih0p, 768, 512);
    PK(ghh0, ghh0p, 768, 256);
    PK(gih1, gih1p, 768, 256);
    PK(ghh1, ghh1p, 768, 256);
    PK(pxw1, pxw1p, 256, 128);
    PK(pxw2, pxw2p, 256, 256);
    PK(dw1, dw1p, 256, 512);
    PK(dw2, dw2p, 256, 256);
    PK(dmw, decp, 128, 256);
    PK(dsw, decp + 128 * 256, 128, 256);
    PK(prw, prwp, 256, 256);
    pack_pair<<<(128 * 256 + 255) / 256, 256, 0, stream>>>(pmw, psw, priorp, 256);
    cvt_bf16<<<2048, 256, 0, stream>>>(x, xbf, TB_ * F_);

    // ---- phase 1: phi_x ----
    dim3 blk(256);
    gemmB<0><<<dim3(2, TB_ / 128), blk, 0, stream>>>(
        xbf, 128, nullptr, 0, (const bh8*)pxw1p, 4, pxb1, nullptr, t1, 256, nullptr,
        nullptr, nullptr, nullptr, nullptr);
    gemmB<0><<<dim3(2, TB_ / 128), blk, 0, stream>>>(
        t1, 256, nullptr, 0, (const bh8*)pxw2p, 8, pxb2, nullptr, phi_x, 256, nullptr,
        nullptr, nullptr, nullptr, nullptr);

    // ---- phase 2: persistent scan ----
    scan_kernel<<<16, 512, 0, stream>>>(
        phi_x, eps, (const bh8*)ew1p, eb1, (const bh8*)ew2p, eb2, (const bh8*)emwp, emb,
        (const bh8*)eswp, esb, (const bh8*)pzw1p, pzb1, (const bh8*)pzw2p, pzb2,
        (const bh8*)gih0p, (const bh8*)ghh0p, (const bh8*)gih1p, (const bh8*)ghh1p,
        em_out, es_out, phi_z, hst);

    // ---- phase 3: decoder / prior / reductions ----
    gemmB<0><<<dim3(2, TB_ / 128), blk, 0, stream>>>(
        phi_z, 256, hst, 256, (const bh8*)dw1p, 16, db1, nullptr, t1, 256, nullptr,
        nullptr, nullptr, nullptr, nullptr);
    gemmB<0><<<dim3(2, TB_ / 128), blk, 0, stream>>>(
        t1, 256, nullptr, 0, (const bh8*)dw2p, 8, db2, nullptr, dox, 256, nullptr,
        nullptr, nullptr, nullptr, nullptr);
    gemmB<1><<<dim3(2, TB_ / 128), blk, 0, stream>>>(
        dox, 256, nullptr, 0, (const bh8*)decp, 8, dmb, dsb, nullptr, 0, dm_out, ds_out,
        x, nullptr, nllp);
    gemmB<0><<<dim3(2, TB_ / 128), blk, 0, stream>>>(
        hst, 256, nullptr, 0, (const bh8*)prwp, 8, prb, nullptr, t1, 256, nullptr,
        nullptr, nullptr, nullptr, nullptr);
    gemmB<2><<<dim3(1, TB_ / 128), blk, 0, stream>>>(
        t1, 256, nullptr, 0, (const bh8*)priorp, 8, pmb, psb, nullptr, 0, nullptr,
        nullptr, em_out, es_out, kldp);

    final_reduce<<<2, 256, 0, stream>>>(kldp, (int)(TB_ / 128), nllp,
                                        (int)(2 * (TB_ / 128)), out);
}

// Round 3
// 33276.038 us; speedup vs baseline: 1.6553x; 1.5915x over previous
//
#include <hip/hip_runtime.h>
#include <hip/hip_bf16.h>
#include <math.h>

#define T_ 512
#define B_ 256
#define F_ 128
#define L_ 64
#define TB_ ((size_t)T_ * B_)

typedef short bh8 __attribute__((ext_vector_type(8)));
typedef float f32x4 __attribute__((ext_vector_type(4)));
typedef unsigned short u16;
typedef unsigned int u32;

#define MFMA16(a, b, c) __builtin_amdgcn_mfma_f32_16x16x32_bf16((a), (b), (c), 0, 0, 0)

__device__ __forceinline__ float sigmoidf_(float x) { return 1.f / (1.f + __expf(-x)); }
__device__ __forceinline__ float softplusf_(float x) {
    return fmaxf(x, 0.f) + log1pf(expf(-fabsf(x)));
}
__device__ __forceinline__ u16 bf16bits(float v) {
    __hip_bfloat16 h = __float2bfloat16(v);
    return *reinterpret_cast<u16*>(&h);
}

// ---------------------------------------------------------------------------
// Weight packing: fp32 [N][K] row-major -> bf16 MFMA-B fragments.
// ---------------------------------------------------------------------------
__global__ __launch_bounds__(256) void pack_w(const float* __restrict__ src,
                                              u16* __restrict__ dst, int N, int K) {
    int idx = blockIdx.x * 256 + threadIdx.x;
    if (idx >= N * K) return;
    int n = idx / K, k = idx - n * K;
    int nt = n >> 4, kt = k >> 5, KT = K >> 5;
    size_t di = ((size_t)(nt * KT + kt) * 64 + ((k >> 3) & 3) * 16 + (n & 15)) * 8 + (k & 7);
    dst[di] = bf16bits(src[idx]);
}

__global__ __launch_bounds__(256) void pack_pair(const float* __restrict__ sA,
                                                 const float* __restrict__ sB,
                                                 u16* __restrict__ dst, int K) {
    int idx = blockIdx.x * 256 + threadIdx.x;
    if (idx >= 128 * K) return;
    int n = idx / K, k = idx - n * K;
    int nt = n >> 4, nin = n & 15, KT = K >> 5;
    const float* s = (nt & 1) ? sB : sA;
    float v = s[(size_t)((nt >> 1) * 16 + nin) * K + k];
    size_t di = ((size_t)(nt * KT + (k >> 5)) * 64 + ((k >> 3) & 3) * 16 + nin) * 8 + (k & 7);
    dst[di] = bf16bits(v);
}

__global__ __launch_bounds__(256) void cvt_bf16(const float* __restrict__ src,
                                                u16* __restrict__ dst, size_t n) {
    for (size_t i = blockIdx.x * 256ull + threadIdx.x; i < n; i += (size_t)gridDim.x * 256)
        dst[i] = bf16bits(src[i]);
}

__global__ __launch_bounds__(256) void init_flags(int* flags) {
    flags[blockIdx.x * 256 + threadIdx.x] = 0;
}

// ---------------------------------------------------------------------------
// Batched MFMA GEMM (pre/post phases) — unchanged from round 2 (verified).
// ---------------------------------------------------------------------------
template <int EPI>
__global__ __launch_bounds__(256) void gemmB(
    const u16* __restrict__ A1, int K1, const u16* __restrict__ A2, int K2,
    const bh8* __restrict__ Wp, int KT,
    const float* __restrict__ b1, const float* __restrict__ b2,
    u16* __restrict__ obf, int Nout,
    float* __restrict__ o1, float* __restrict__ o2,
    const float* __restrict__ aux1, const float* __restrict__ aux2,
    float* __restrict__ partial) {
    __shared__ __align__(16) char As[8192];
    __shared__ float red[256];
    const int tid = threadIdx.x, w = tid >> 6, l = tid & 63, l15 = l & 15, lq = l >> 4;
    const int wr = w >> 1, wc = w & 1;
    const size_t m0 = (size_t)blockIdx.y * 128;
    f32x4 acc[4][4];
#pragma unroll
    for (int i = 0; i < 4; ++i)
#pragma unroll
        for (int j = 0; j < 4; ++j) acc[i][j] = f32x4{0.f, 0.f, 0.f, 0.f};

    for (int kt = 0; kt < KT; ++kt) {
#pragma unroll
        for (int cc = 0; cc < 2; ++cc) {
            int c = tid + cc * 256;
            int r = c >> 2, j = c & 3;
            int kg = kt * 32 + j * 8;
            const u16* src = (kg < K1) ? (A1 + (m0 + r) * (size_t)K1 + kg)
                                       : (A2 + (m0 + r) * (size_t)K2 + (kg - K1));
            bh8 v = *(const bh8*)src;
            *(bh8*)(As + r * 64 + ((j * 16) ^ ((r & 7) << 4))) = v;
        }
        __syncthreads();
        bh8 bfr[4];
#pragma unroll
        for (int nt = 0; nt < 4; ++nt)
            bfr[nt] = Wp[((size_t)(blockIdx.x * 8 + wc * 4 + nt) * KT + kt) * 64 + l];
#pragma unroll
        for (int mt = 0; mt < 4; ++mt) {
            int rrow = (wr * 4 + mt) * 16 + l15;
            bh8 a = *(const bh8*)(As + rrow * 64 + ((lq * 16) ^ ((rrow & 7) << 4)));
#pragma unroll
            for (int nt = 0; nt < 4; ++nt) acc[mt][nt] = MFMA16(a, bfr[nt], acc[mt][nt]);
        }
        __syncthreads();
    }

    float part = 0.f;
#pragma unroll
    for (int mt = 0; mt < 4; ++mt) {
        if (EPI == 0 || EPI == 1) {
#pragma unroll
            for (int nt = 0; nt < 4; ++nt) {
                int gt = blockIdx.x * 8 + wc * 4 + nt;
#pragma unroll
                for (int rr = 0; rr < 4; ++rr) {
                    size_t row = m0 + (wr * 4 + mt) * 16 + lq * 4 + rr;
                    float v = acc[mt][nt][rr];
                    if (EPI == 0) {
                        int col = gt * 16 + l15;
                        obf[row * Nout + col] = bf16bits(fmaxf(v + b1[col], 0.f));
                    } else {
                        if (gt < 8) {
                            int col = gt * 16 + l15;
                            float u = v + b1[col];
                            o1[row * 128 + col] = sigmoidf_(u);
                            float xv = aux1[row * 128 + col];
                            part += xv * softplusf_(-u) + (1.f - xv) * softplusf_(u);
                        } else {
                            int col = (gt - 8) * 16 + l15;
                            o2[row * 128 + col] = softplusf_(v + b2[col]);
                        }
                    }
                }
            }
        } else {
#pragma unroll
            for (int np = 0; np < 2; ++np) {
                int col = (wc * 2 + np) * 16 + l15;
#pragma unroll
                for (int rr = 0; rr < 4; ++rr) {
                    size_t row = m0 + (wr * 4 + mt) * 16 + lq * 4 + rr;
                    float um = acc[mt][2 * np][rr] + b1[col];
                    float us = acc[mt][2 * np + 1][rr] + b2[col];
                    float pm = sigmoidf_(um);
                    float ps = softplusf_(us);
                    float em = aux1[row * 64 + col];
                    float es = aux2[row * 64 + col];
                    float d = em - pm;
                    part += 0.5f * (2.f * (logf(ps) - logf(es)) +
                                    (es * es + d * d) / (ps * ps) - 1.f);
                }
            }
        }
    }
    if (EPI != 0) {
        __syncthreads();
        red[tid] = part;
        __syncthreads();
        for (int s = 128; s > 0; s >>= 1) {
            if (tid < s) red[tid] += red[tid + s];
            __syncthreads();
        }
        if (tid == 0) partial[(size_t)blockIdx.y * gridDim.x + blockIdx.x] = red[0];
    }
}

// ---------------------------------------------------------------------------
// Cooperative scan: 8 groups (32 batch rows) x 8 column-slice WGs = 64 WGs.
// Group-local epoch barriers via agent-scope atomics; handoffs via relaxed
// L1-bypassing atomic u32 loads/stores. bid = c*8+g keeps a group on one XCD.
// ---------------------------------------------------------------------------
#define CAT 0          // [32][512] bf16 (stride 1024): phi_x | h1/phi_z
#define H0B 32768      // [32][256] bf16 (512): h0 (then h0_new)
#define GBUF 49152     // [32][256] bf16 (512): e1 -> eo -> pz1
#define ZB 65536       // [32][64]  bf16 (128)
#define GH0L 69632     // [32][96] f32 (384)
#define GH1L 81920     // [32][96] f32
#define GIL 94208      // [2][32][96] f32 (kh stride 12288)
#define EMF 118784     // [32][64] f32 (256)
#define ESF 126976     // [32][64] f32
#define SMEM_BYTES 135168

__device__ __forceinline__ u32 aload_(const u32* p) {
    return __hip_atomic_load(p, __ATOMIC_RELAXED, __HIP_MEMORY_SCOPE_AGENT);
}
__device__ __forceinline__ void astore_(u32* p, u32 v) {
    __hip_atomic_store(p, v, __ATOMIC_RELAXED, __HIP_MEMORY_SCOPE_AGENT);
}

template <int NKT>
__device__ __forceinline__ void mm32t(const char* smem, int base, int rstride,
                                      int kbyte0, const bh8* wb, int l15, int lq,
                                      f32x4& a0, f32x4& a1) {
    const int sw = (l15 & 7) << 4;
#pragma unroll
    for (int kt = 0; kt < NKT; ++kt) {
        int kb = kbyte0 + kt * 64 + lq * 16;
        bh8 af0 = *(const bh8*)(smem + base + l15 * rstride + (kb ^ sw));
        bh8 af1 = *(const bh8*)(smem + base + (l15 + 16) * rstride + (kb ^ sw));
        bh8 bf = wb[kt * 64];
        a0 = MFMA16(af0, bf, a0);
        a1 = MFMA16(af1, bf, a1);
    }
}

__global__ __launch_bounds__(512, 1) void scan_kernel(
    const u16* __restrict__ phix_g, const float* __restrict__ eps_g,
    const bh8* __restrict__ ew1p, const float* __restrict__ eb1,
    const bh8* __restrict__ ew2p, const float* __restrict__ eb2,
    const bh8* __restrict__ emwp, const float* __restrict__ emb,
    const bh8* __restrict__ eswp, const float* __restrict__ esb,
    const bh8* __restrict__ pzw1p, const float* __restrict__ pzb1,
    const bh8* __restrict__ pzw2p, const float* __restrict__ pzb2,
    const bh8* __restrict__ gih0p, const bh8* __restrict__ ghh0p,
    const bh8* __restrict__ gih1p, const bh8* __restrict__ ghh1p,
    float* __restrict__ em_out, float* __restrict__ es_out,
    u16* __restrict__ phiz_g, u16* __restrict__ hst_g,
    u16* __restrict__ hand, int* __restrict__ flags) {
    __shared__ __align__(16) char smem[SMEM_BYTES];
    const int tid = threadIdx.x;
    const int w = tid >> 6, l = tid & 63, l15 = l & 15, lq = l >> 4;
    const int bid = blockIdx.x;
    const int c = bid >> 3, g = bid & 7;   // slice, group (group g -> XCD g)
    const int row0 = g * 32;

    u16* E1G = hand + (size_t)g * 8192;
    u16* EOG = hand + (size_t)(8 + g) * 8192;
    u16* PHZG = hand + (size_t)(16 + g) * 8192;
    u16* H0G = hand + (size_t)(24 + g) * 8192;
    u16* H1G = hand + (size_t)(32 + g) * 8192;

    auto gbar = [&](int s, int target) {
        __syncthreads();
        if (tid == 0) {
            int* f = flags + (g * 8 + s) * 32;
            __hip_atomic_fetch_add(f, 1, __ATOMIC_RELEASE, __HIP_MEMORY_SCOPE_AGENT);
            while (__hip_atomic_load(f, __ATOMIC_RELAXED, __HIP_MEMORY_SCOPE_AGENT) <
                   target) {
            }
            (void)__hip_atomic_load(f, __ATOMIC_ACQUIRE, __HIP_MEMORY_SCOPE_AGENT);
        }
        __syncthreads();
    };

    // load a [32][256]-bf16 handoff buffer into LDS (swizzled), atomic u32 reads
    auto load_hand = [&](const u16* gb, int base, int rstride, int cbyte0) {
#pragma unroll
        for (int k = 0; k < 8; ++k) {
            int j = tid + k * 512;
            int r = j >> 7, cu = j & 127;
            u32 v = aload_((const u32*)gb + j);
            *(u32*)(smem + base + r * rstride + cbyte0 + ((cu * 4) ^ ((r & 7) << 4))) = v;
        }
    };

    // ---- pre-loop init ----
    float h0m[2] = {0.f, 0.f}, h1m[2] = {0.f, 0.f};
    for (int i = tid * 16; i < 16384; i += 512 * 16)
        *(int4*)(smem + H0B + i) = int4{0, 0, 0, 0};
    {
        int row = tid >> 4, pc = tid & 15;
        astore_((u32*)(H0G + row * 256 + 32 * c + pc * 2), 0u);
        astore_((u32*)(H1G + row * 256 + 32 * c + pc * 2), 0u);
        *(u32*)(hst_g + (size_t)(row0 + row) * 256 + 32 * c + pc * 2) = 0u;
    }
    gbar(4, 8);

    for (int t = 0; t < T_; ++t) {
        // ---- loop-top: CAT <- phi_x | h1 ----
#pragma unroll
        for (int k = 0; k < 2; ++k) {
            int i = tid + k * 512;
            int r = i >> 5, ch = i & 31;
            bh8 v = *(const bh8*)(phix_g + ((size_t)t * B_ + row0 + r) * 256 + ch * 8);
            *(bh8*)(smem + CAT + r * 1024 + ((ch * 16) ^ ((r & 7) << 4))) = v;
        }
        load_hand(H1G, CAT, 1024, 512);
        __syncthreads();

        // ---- S1: e1 (waves 0-1) + gh0/gh1 (waves 2-7) ----
        if (w < 2) {
            int gt = 2 * c + w;
            f32x4 a0 = {0.f, 0.f, 0.f, 0.f}, a1 = {0.f, 0.f, 0.f, 0.f};
            mm32t<16>(smem, CAT, 1024, 0, ew1p + (size_t)gt * 16 * 64 + l, l15, lq, a0, a1);
#pragma unroll
            for (int rt = 0; rt < 2; ++rt) {
                f32x4& a = rt ? a1 : a0;
#pragma unroll
                for (int rr = 0; rr < 4; ++rr) {
                    int row = rt * 16 + lq * 4 + rr;
                    int col = gt * 16 + l15;
                    float v = fmaxf(a[rr] + eb1[col], 0.f);
                    int bits = (int)bf16bits(v);
                    int pb = __shfl_xor(bits, 1);
                    if (!(l15 & 1))
                        astore_((u32*)(E1G + row * 256 + col),
                                ((u32)bits & 0xffffu) | ((u32)pb << 16));
                }
            }
        } else {
            int j = w - 2;
            int gt = (j < 2) ? (2 * c + j)
                             : (j < 4) ? (16 + 2 * c + j - 2) : (32 + 2 * c + j - 4);
            f32x4 a0 = {0.f, 0.f, 0.f, 0.f}, a1 = {0.f, 0.f, 0.f, 0.f};
            mm32t<8>(smem, H0B, 512, 0, ghh0p + (size_t)gt * 8 * 64 + l, l15, lq, a0, a1);
#pragma unroll
            for (int rt = 0; rt < 2; ++rt) {
                f32x4& a = rt ? a1 : a0;
#pragma unroll
                for (int rr = 0; rr < 4; ++rr) {
                    int row = rt * 16 + lq * 4 + rr;
                    *(float*)(smem + GH0L + row * 384 + (j * 16 + l15) * 4) = a[rr];
                }
            }
            f32x4 b0 = {0.f, 0.f, 0.f, 0.f}, b1v = {0.f, 0.f, 0.f, 0.f};
            mm32t<8>(smem, CAT, 1024, 512, ghh1p + (size_t)gt * 8 * 64 + l, l15, lq, b0, b1v);
#pragma unroll
            for (int rt = 0; rt < 2; ++rt) {
                f32x4& a = rt ? b1v : b0;
#pragma unroll
                for (int rr = 0; rr < 4; ++rr) {
                    int row = rt * 16 + lq * 4 + rr;
                    *(float*)(smem + GH1L + row * 384 + (j * 16 + l15) * 4) = a[rr];
                }
            }
        }
        gbar(0, 8 * (t + 1));

        // ---- S2: eo (4-wave split-K) ----
        load_hand(E1G, GBUF, 512, 0);
        __syncthreads();
        if (w < 4) {
            int tl = w >> 1, kh = w & 1;
            int gt = 2 * c + tl;
            f32x4 a0 = {0.f, 0.f, 0.f, 0.f}, a1 = {0.f, 0.f, 0.f, 0.f};
            mm32t<4>(smem, GBUF, 512, kh * 256,
                     ew2p + ((size_t)gt * 8 + kh * 4) * 64 + l, l15, lq, a0, a1);
#pragma unroll
            for (int rt = 0; rt < 2; ++rt) {
                f32x4& a = rt ? a1 : a0;
#pragma unroll
                for (int rr = 0; rr < 4; ++rr) {
                    int row = rt * 16 + lq * 4 + rr;
                    *(float*)(smem + GIL + row * 384 + (w * 16 + l15) * 4) = a[rr];
                }
            }
        }
        __syncthreads();
        {
            int row = tid >> 4, cl0 = (tid & 15) * 2;
            u32 pv = 0;
#pragma unroll
            for (int q = 0; q < 2; ++q) {
                int cl = cl0 + q, tl = cl >> 4, ci = cl & 15;
                float v = *(float*)(smem + GIL + row * 384 + (tl * 32 + ci) * 4) +
                          *(float*)(smem + GIL + row * 384 + (tl * 32 + 16 + ci) * 4);
                int colg = 32 * c + cl;
                v = fmaxf(v + eb2[colg], 0.f);
                pv |= ((u32)bf16bits(v)) << (16 * q);
            }
            astore_((u32*)(EOG + row * 256 + 32 * c + cl0), pv);
        }
        gbar(1, 8 * (t + 1));

        // ---- S3: em/es full-redundant (wave w: tile w&3 of em(w<4)/es) ----
        load_hand(EOG, GBUF, 512, 0);
        __syncthreads();
        {
            int tl = w & 3;
            const bh8* wb = ((w < 4) ? emwp : eswp) + (size_t)tl * 8 * 64 + l;
            f32x4 a0 = {0.f, 0.f, 0.f, 0.f}, a1 = {0.f, 0.f, 0.f, 0.f};
            mm32t<8>(smem, GBUF, 512, 0, wb, l15, lq, a0, a1);
            int ebase = (w < 4) ? EMF : ESF;
            const float* bias = (w < 4) ? emb : esb;
            float* stash = (w < 4) ? em_out : es_out;
#pragma unroll
            for (int rt = 0; rt < 2; ++rt) {
                f32x4& a = rt ? a1 : a0;
#pragma unroll
                for (int rr = 0; rr < 4; ++rr) {
                    int row = rt * 16 + lq * 4 + rr;
                    int colL = tl * 16 + l15;
                    float u_ = a[rr] + bias[colL];
                    float v = (w < 4) ? sigmoidf_(u_) : softplusf_(u_);
                    *(float*)(smem + ebase + row * 256 + colL * 4) = v;
                    if (w == c)
                        stash[((size_t)t * B_ + row0 + row) * 64 + colL] = v;
                }
            }
        }
        __syncthreads();

        // ---- z = eps*es + em -> ZB ----
#pragma unroll
        for (int k = 0; k < 4; ++k) {
            int idx = tid + k * 512;
            int row = idx >> 6, cz = idx & 63;
            float es_ = *(float*)(smem + ESF + row * 256 + cz * 4);
            float em_ = *(float*)(smem + EMF + row * 256 + cz * 4);
            float zv = eps_g[((size_t)t * B_ + row0 + row) * 64 + cz] * es_ + em_;
            *(u16*)(smem + ZB + row * 128 + ((cz * 2) ^ ((row & 7) << 4))) = bf16bits(zv);
        }
        __syncthreads();

        // ---- S4: pz1 full-redundant (2 tiles/wave) -> GBUF ----
#pragma unroll
        for (int ti = 0; ti < 2; ++ti) {
            int nt = w * 2 + ti;
            f32x4 a0 = {0.f, 0.f, 0.f, 0.f}, a1 = {0.f, 0.f, 0.f, 0.f};
            mm32t<2>(smem, ZB, 128, 0, pzw1p + (size_t)nt * 2 * 64 + l, l15, lq, a0, a1);
#pragma unroll
            for (int rt = 0; rt < 2; ++rt) {
                f32x4& a = rt ? a1 : a0;
#pragma unroll
                for (int rr = 0; rr < 4; ++rr) {
                    int row = rt * 16 + lq * 4 + rr;
                    int col = nt * 16 + l15;
                    float v = fmaxf(a[rr] + pzb1[col], 0.f);
                    *(u16*)(smem + GBUF + row * 512 + ((col * 2) ^ ((row & 7) << 4))) =
                        bf16bits(v);
                }
            }
        }
        __syncthreads();

        // ---- S5: phi_z (4-wave split-K) ----
        if (w < 4) {
            int tl = w >> 1, kh = w & 1;
            int gt = 2 * c + tl;
            f32x4 a0 = {0.f, 0.f, 0.f, 0.f}, a1 = {0.f, 0.f, 0.f, 0.f};
            mm32t<4>(smem, GBUF, 512, kh * 256,
                     pzw2p + ((size_t)gt * 8 + kh * 4) * 64 + l, l15, lq, a0, a1);
#pragma unroll
            for (int rt = 0; rt < 2; ++rt) {
                f32x4& a = rt ? a1 : a0;
#pragma unroll
                for (int rr = 0; rr < 4; ++rr) {
                    int row = rt * 16 + lq * 4 + rr;
                    *(float*)(smem + GIL + row * 384 + (w * 16 + l15) * 4) = a[rr];
                }
            }
        }
        __syncthreads();
        {
            int row = tid >> 4, cl0 = (tid & 15) * 2;
            u32 pv = 0;
#pragma unroll
            for (int q = 0; q < 2; ++q) {
                int cl = cl0 + q, tl = cl >> 4, ci = cl & 15;
                float v = *(float*)(smem + GIL + row * 384 + (tl * 32 + ci) * 4) +
                          *(float*)(smem + GIL + row * 384 + (tl * 32 + 16 + ci) * 4);
                int colg = 32 * c + cl;
                v = fmaxf(v + pzb2[colg], 0.f);
                pv |= ((u32)bf16bits(v)) << (16 * q);
            }
            astore_((u32*)(PHZG + row * 256 + 32 * c + cl0), pv);
            *(u32*)(phiz_g + ((size_t)t * B_ + row0 + row) * 256 + 32 * c + cl0) = pv;
        }
        gbar(2, 8 * (t + 1));

        // ---- S6: gi0 (12 split-K units) + GRU0 gates ----
        load_hand(PHZG, CAT, 1024, 512);
        __syncthreads();
        {
            auto dos6 = [&](int u) {
                int lt = u % 6, kh = u / 6;
                int gt = (lt < 2) ? (2 * c + lt)
                                  : (lt < 4) ? (16 + 2 * c + lt - 2) : (32 + 2 * c + lt - 4);
                f32x4 a0 = {0.f, 0.f, 0.f, 0.f}, a1 = {0.f, 0.f, 0.f, 0.f};
                mm32t<8>(smem, CAT, 1024, kh * 512,
                         gih0p + ((size_t)gt * 16 + kh * 8) * 64 + l, l15, lq, a0, a1);
#pragma unroll
                for (int rt = 0; rt < 2; ++rt) {
                    f32x4& a = rt ? a1 : a0;
#pragma unroll
                    for (int rr = 0; rr < 4; ++rr) {
                        int row = rt * 16 + lq * 4 + rr;
                        *(float*)(smem + GIL + kh * 12288 + row * 384 + (lt * 16 + l15) * 4) =
                            a[rr];
                    }
                }
            };
            dos6(w);
            if (w < 4) dos6(w + 8);
        }
        __syncthreads();
        {
            int row = tid >> 4, pc = tid & 15;
            u32 pv = 0;
#pragma unroll
            for (int q = 0; q < 2; ++q) {
                int lc = pc * 2 + q;
                float gir = *(float*)(smem + GIL + row * 384 + lc * 4) +
                            *(float*)(smem + GIL + 12288 + row * 384 + lc * 4);
                float giz = *(float*)(smem + GIL + row * 384 + (32 + lc) * 4) +
                            *(float*)(smem + GIL + 12288 + row * 384 + (32 + lc) * 4);
                float gin = *(float*)(smem + GIL + row * 384 + (64 + lc) * 4) +
                            *(float*)(smem + GIL + 12288 + row * 384 + (64 + lc) * 4);
                float ghr = *(float*)(smem + GH0L + row * 384 + lc * 4);
                float ghz = *(float*)(smem + GH0L + row * 384 + (32 + lc) * 4);
                float ghn = *(float*)(smem + GH0L + row * 384 + (64 + lc) * 4);
                float gr = sigmoidf_(gir + ghr);
                float gz = sigmoidf_(giz + ghz);
                float gn = tanhf(gin + gr * ghn);
                float hn = (1.f - gz) * gn + gz * h0m[q];
                h0m[q] = hn;
                pv |= ((u32)bf16bits(hn)) << (16 * q);
            }
            astore_((u32*)(H0G + row * 256 + 32 * c + pc * 2), pv);
        }
        gbar(3, 8 * (t + 1));

        // ---- S7: gi1 (12 split-K units) + GRU1 gates ----
        load_hand(H0G, H0B, 512, 0);
        __syncthreads();
        {
            auto dos7 = [&](int u) {
                int lt = u % 6, kh = u / 6;
                int gt = (lt < 2) ? (2 * c + lt)
                                  : (lt < 4) ? (16 + 2 * c + lt - 2) : (32 + 2 * c + lt - 4);
                f32x4 a0 = {0.f, 0.f, 0.f, 0.f}, a1 = {0.f, 0.f, 0.f, 0.f};
                mm32t<4>(smem, H0B, 512, kh * 256,
                         gih1p + ((size_t)gt * 8 + kh * 4) * 64 + l, l15, lq, a0, a1);
#pragma unroll
                for (int rt = 0; rt < 2; ++rt) {
                    f32x4& a = rt ? a1 : a0;
#pragma unroll
                    for (int rr = 0; rr < 4; ++rr) {
                        int row = rt * 16 + lq * 4 + rr;
                        *(float*)(smem + GIL + kh * 12288 + row * 384 + (lt * 16 + l15) * 4) =
                            a[rr];
                    }
                }
            };
            dos7(w);
            if (w < 4) dos7(w + 8);
        }
        __syncthreads();
        {
            int row = tid >> 4, pc = tid & 15;
            u32 pv = 0;
#pragma unroll
            for (int q = 0; q < 2; ++q) {
                int lc = pc * 2 + q;
                float gir = *(float*)(smem + GIL + row * 384 + lc * 4) +
                            *(float*)(smem + GIL + 12288 + row * 384 + lc * 4);
                float giz = *(float*)(smem + GIL + row * 384 + (32 + lc) * 4) +
                            *(float*)(smem + GIL + 12288 + row * 384 + (32 + lc) * 4);
                float gin = *(float*)(smem + GIL + row * 384 + (64 + lc) * 4) +
                            *(float*)(smem + GIL + 12288 + row * 384 + (64 + lc) * 4);
                float ghr = *(float*)(smem + GH1L + row * 384 + lc * 4);
                float ghz = *(float*)(smem + GH1L + row * 384 + (32 + lc) * 4);
                float ghn = *(float*)(smem + GH1L + row * 384 + (64 + lc) * 4);
                float gr = sigmoidf_(gir + ghr);
                float gz = sigmoidf_(giz + ghz);
                float gn = tanhf(gin + gr * ghn);
                float hn = (1.f - gz) * gn + gz * h1m[q];
                h1m[q] = hn;
                pv |= ((u32)bf16bits(hn)) << (16 * q);
            }
            astore_((u32*)(H1G + row * 256 + 32 * c + pc * 2), pv);
            if (t < T_ - 1)
                *(u32*)(hst_g + ((size_t)(t + 1) * B_ + row0 + row) * 256 + 32 * c +
                        pc * 2) = pv;
        }
        gbar(4, 8 * (t + 2));
    }
}

__global__ __launch_bounds__(256) void final_reduce(const float* __restrict__ kldp,
                                                    int n_kld,
                                                    const float* __restrict__ nllp,
                                                    int n_nll, float* __restrict__ out) {
    const float* src = (blockIdx.x == 0) ? kldp : nllp;
    int n = (blockIdx.x == 0) ? n_kld : n_nll;
    __shared__ float red[256];
    int tid = threadIdx.x;
    float s = 0.f;
    for (int i = tid; i < n; i += 256) s += src[i];
    red[tid] = s;
    __syncthreads();
    for (int st = 128; st > 0; st >>= 1) {
        if (tid < st) red[tid] += red[tid + st];
        __syncthreads();
    }
    if (tid == 0) out[blockIdx.x] = red[0];
}

extern "C" void kernel_launch(void* const* d_in, const int* in_sizes, int n_in,
                              void* d_out, int out_size, void* d_ws, size_t ws_size,
                              hipStream_t stream) {
    const float* x = (const float*)d_in[0];
    const float* eps = (const float*)d_in[1];
    const float* pxw1 = (const float*)d_in[2];
    const float* pxb1 = (const float*)d_in[3];
    const float* pxw2 = (const float*)d_in[4];
    const float* pxb2 = (const float*)d_in[5];
    const float* pzw1 = (const float*)d_in[6];
    const float* pzb1 = (const float*)d_in[7];
    const float* pzw2 = (const float*)d_in[8];
    const float* pzb2 = (const float*)d_in[9];
    const float* ew1 = (const float*)d_in[10];
    const float* eb1 = (const float*)d_in[11];
    const float* ew2 = (const float*)d_in[12];
    const float* eb2 = (const float*)d_in[13];
    const float* emw = (const float*)d_in[14];
    const float* emb = (const float*)d_in[15];
    const float* esw = (const float*)d_in[16];
    const float* esb = (const float*)d_in[17];
    const float* prw = (const float*)d_in[18];
    const float* prb = (const float*)d_in[19];
    const float* pmw = (const float*)d_in[20];
    const float* pmb = (const float*)d_in[21];
    const float* psw = (const float*)d_in[22];
    const float* psb = (const float*)d_in[23];
    const float* dw1 = (const float*)d_in[24];
    const float* db1 = (const float*)d_in[25];
    const float* dw2 = (const float*)d_in[26];
    const float* db2 = (const float*)d_in[27];
    const float* dmw = (const float*)d_in[28];
    const float* dmb = (const float*)d_in[29];
    const float* dsw = (const float*)d_in[30];
    const float* dsb = (const float*)d_in[31];
    const float* gih0 = (const float*)d_in[32];
    const float* ghh0 = (const float*)d_in[33];
    const float* gih1 = (const float*)d_in[34];
    const float* ghh1 = (const float*)d_in[35];

    float* out = (float*)d_out;
    char* wsb = (char*)d_ws;

    u16* ew1p = (u16*)(wsb + 0);
    u16* ew2p = (u16*)(wsb + 262144);
    u16* emwp = (u16*)(wsb + 393216);
    u16* eswp = (u16*)(wsb + 425984);
    u16* pzw1p = (u16*)(wsb + 458752);
    u16* pzw2p = (u16*)(wsb + 491520);
    u16* gih0p = (u16*)(wsb + 622592);
    u16* ghh0p = (u16*)(wsb + 1409024);
    u16* gih1p = (u16*)(wsb + 1802240);
    u16* ghh1p = (u16*)(wsb + 2195456);
    u16* pxw1p = (u16*)(wsb + 2588672);
    u16* pxw2p = (u16*)(wsb + 2654208);
    u16* dw1p = (u16*)(wsb + 2785280);
    u16* dw2p = (u16*)(wsb + 3047424);
    u16* decp = (u16*)(wsb + 3178496);
    u16* priorp = (u16*)(wsb + 3309568);
    u16* prwp = (u16*)(wsb + 3375104);

    u16* xbf = (u16*)(wsb + 3506176);
    // handoff + flags live inside the xbf region (xbf only used before the scan)
    u16* hand = (u16*)(wsb + 3506176);
    int* flags = (int*)(wsb + 3506176 + 1048576);

    u16* t1 = (u16*)(wsb + 37060608);
    u16* phi_x = (u16*)(wsb + 104169472);
    u16* phi_z = (u16*)(wsb + 171278336);
    u16* hst = (u16*)(wsb + 238387200);
    u16* dox = (u16*)(wsb + 305496064);
    float* nllp = (float*)(wsb + 372604928);
    float* kldp = (float*)(wsb + 372613120);

    float* em_out = out + 2;
    float* es_out = em_out + TB_ * L_;
    float* dm_out = es_out + TB_ * L_;
    float* ds_out = dm_out + TB_ * F_;

    auto PK = [&](const float* s, u16* d, int N, int K) {
        pack_w<<<(N * K + 255) / 256, 256, 0, stream>>>(s, d, N, K);
    };
    PK(ew1, ew1p, 256, 512);
    PK(ew2, ew2p, 256, 256);
    PK(emw, emwp, 64, 256);
    PK(esw, eswp, 64, 256);
    PK(pzw1, pzw1p, 256, 64);
    PK(pzw2, pzw2p, 256, 256);
    PK(gih0, gih0p, 768, 512);
    PK(ghh0, ghh0p, 768, 256);
    PK(gih1, gih1p, 768, 256);
    PK(ghh1, ghh1p, 768, 256);
    PK(pxw1, pxw1p, 256, 128);
    PK(pxw2, pxw2p, 256, 256);
    PK(dw1, dw1p, 256, 512);
    PK(dw2, dw2p, 256, 256);
    PK(dmw, decp, 128, 256);
    PK(dsw, decp + 128 * 256, 128, 256);
    PK(prw, prwp, 256, 256);
    pack_pair<<<(128 * 256 + 255) / 256, 256, 0, stream>>>(pmw, psw, priorp, 256);
    cvt_bf16<<<2048, 256, 0, stream>>>(x, xbf, TB_ * F_);

    // ---- phase 1: phi_x (reads xbf; must precede init_flags/scan) ----
    dim3 blk(256);
    gemmB<0><<<dim3(2, TB_ / 128), blk, 0, stream>>>(
        xbf, 128, nullptr, 0, (const bh8*)pxw1p, 4, pxb1, nullptr, t1, 256, nullptr,
        nullptr, nullptr, nullptr, nullptr);
    gemmB<0><<<dim3(2, TB_ / 128), blk, 0, stream>>>(
        t1, 256, nullptr, 0, (const bh8*)pxw2p, 8, pxb2, nullptr, phi_x, 256, nullptr,
        nullptr, nullptr, nullptr, nullptr);

    init_flags<<<8, 256, 0, stream>>>(flags);

    // ---- phase 2: cooperative scan ----
    scan_kernel<<<64, 512, 0, stream>>>(
        phi_x, eps, (const bh8*)ew1p, eb1, (const bh8*)ew2p, eb2, (const bh8*)emwp, emb,
        (const bh8*)eswp, esb, (const bh8*)pzw1p, pzb1, (const bh8*)pzw2p, pzb2,
        (const bh8*)gih0p, (const bh8*)ghh0p, (const bh8*)gih1p, (const bh8*)ghh1p,
        em_out, es_out, phi_z, hst, hand, flags);

    // ---- phase 3: decoder / prior / reductions ----
    gemmB<0><<<dim3(2, TB_ / 128), blk, 0, stream>>>(
        phi_z, 256, hst, 256, (const bh8*)dw1p, 16, db1, nullptr, t1, 256, nullptr,
        nullptr, nullptr, nullptr, nullptr);
    gemmB<0><<<dim3(2, TB_ / 128), blk, 0, stream>>>(
        t1, 256, nullptr, 0, (const bh8*)dw2p, 8, db2, nullptr, dox, 256, nullptr,
        nullptr, nullptr, nullptr, nullptr);
    gemmB<1><<<dim3(2, TB_ / 128), blk, 0, stream>>>(
        dox, 256, nullptr, 0, (const bh8*)decp, 8, dmb, dsb, nullptr, 0, dm_out, ds_out,
        x, nullptr, nllp);
    gemmB<0><<<dim3(2, TB_ / 128), blk, 0, stream>>>(
        hst, 256, nullptr, 0, (const bh8*)prwp, 8, prb, nullptr, t1, 256, nullptr,
        nullptr, nullptr, nullptr, nullptr);
    gemmB<2><<<dim3(1, TB_ / 128), blk, 0, stream>>>(
        t1, 256, nullptr, 0, (const bh8*)priorp, 8, pmb, psb, nullptr, 0, nullptr,
        nullptr, em_out, es_out, kldp);

    final_reduce<<<2, 256, 0, stream>>>(kldp, (int)(TB_ / 128), nllp,
                                        (int)(2 * (TB_ / 128)), out);
}